// Round 9
// baseline (200.756 us; speedup 1.0000x reference)
//
#include <hip/hip_runtime.h>

#define B_ 2
#define T_ 2048
#define H_ 1024
#define D_ 64
#define M_ 16
#define BT_ (B_*T_)

#define N_HID (B_*T_*H_)          // 4194304
#define N_W   (M_*H_*D_)          // 1048576
#define N_OW  (M_*D_*H_)          // 1048576
#define N_C   (N_HID + N_OW + 16) // canon: hid + ow + gates
#define NB_CONV 5121              // (N_C/4 + 255)/256

#define OUT_SHA  (B_*T_*H_)       // 4194304
#define OUT_LOG  (2*B_*T_*H_)     // 8388608
#define OUT_MASK (OUT_LOG + B_*M_)
#define OUT_FBC  (OUT_MASK + B_*M_)

typedef __bf16 bf16x8 __attribute__((ext_vector_type(8)));
typedef float floatx4 __attribute__((ext_vector_type(4)));
typedef float floatx16 __attribute__((ext_vector_type(16)));
typedef unsigned int uintx4 __attribute__((ext_vector_type(4)));

__device__ __forceinline__ float bf2f(unsigned short u){
  unsigned int v = ((unsigned int)u) << 16;
  return __builtin_bit_cast(float, v);
}
__device__ __forceinline__ unsigned short f2bfn(float f){
  __bf16 h = (__bf16)f;                       // RNE
  return __builtin_bit_cast(unsigned short, h);
}
__device__ __forceinline__ unsigned int pk2bf(float a, float b){
  return (unsigned int)f2bfn(a) | ((unsigned int)f2bfn(b) << 16);
}
__device__ __forceinline__ void store_out(void* out, int flag, long idx, float v){
  if(flag) ((unsigned short*)out)[idx] = f2bfn(v);
  else     ((float*)out)[idx] = v;
}
__device__ __forceinline__ void gload16(const void* g, void* l){
  __builtin_amdgcn_global_load_lds(
      (const __attribute__((address_space(1))) unsigned int*)g,
      (__attribute__((address_space(3))) unsigned int*)l, 16, 0, 0);
}
// v_permlane32_swap_b32: a.hi <-> b.lo (register-only, data deps via +v)
__device__ __forceinline__ void pl32swap(unsigned int &a, unsigned int &b){
  asm("v_permlane32_swap_b32 %0, %1" : "+v"(a), "+v"(b));
}

// ---------------------------------------------------------------------------
// Kernel P: fused prep = detect + convert + wtrans.
// ---------------------------------------------------------------------------
__global__ __launch_bounds__(256) void prep_kernel(
    const void* __restrict__ p0, const void* __restrict__ p1,
    const void* __restrict__ p2, const void* __restrict__ p3,
    const void* __restrict__ p4, const void* __restrict__ p5,
    unsigned short* __restrict__ canon, unsigned short* __restrict__ WT,
    int* __restrict__ flag_ws, double* __restrict__ aff)
{
  __shared__ int red[4];
  __shared__ __align__(16) unsigned short Tb[64*72];
  const int tid = threadIdx.x;
  const long bid = blockIdx.x;

  // ---- per-block dtype detect ----
  {
    const unsigned int* hw = (const unsigned int*)p0;
    int c = 0;
    #pragma unroll
    for(int i=0;i<4;i++){
      unsigned int e = (hw[tid + i*256] >> 7) & 0xFFu;
      c += (e >= 96u && e <= 144u);
    }
    c += __shfl_xor(c,1); c += __shfl_xor(c,2); c += __shfl_xor(c,4);
    c += __shfl_xor(c,8); c += __shfl_xor(c,16); c += __shfl_xor(c,32);
    if((tid & 63) == 0) red[tid >> 6] = c;
  }
  __syncthreads();
  const int flag = (red[0]+red[1]+red[2]+red[3] > 512) ? 1 : 0;

  if(bid == 0){
    if(tid == 0) *flag_ws = flag;
    if(tid < B_*M_) aff[tid] = 0.0;
  }

  if(bid < NB_CONV){
    // ---- convert role ----
    long i4 = (bid*256 + tid) * 4;
    if(i4 >= N_C) return;
    const void* src; long off;
    if(i4 < N_HID)            { src=p0; off=i4; }
    else if(i4 < N_HID+N_OW)  { src=p4; off=i4-N_HID; }
    else                      { src=p5; off=i4-N_HID-N_OW; }
    unsigned long long r;
    if(flag){
      r = *reinterpret_cast<const unsigned long long*>((const unsigned short*)src + off);
    } else {
      const float* f = (const float*)src + off;
      unsigned long long a = f2bfn(f[0]), b = f2bfn(f[1]), c = f2bfn(f[2]), d = f2bfn(f[3]);
      r = a | (b<<16) | (c<<32) | (d<<48);
    }
    *reinterpret_cast<unsigned long long*>(canon + i4) = r;
  } else {
    // ---- wtrans role ----
    const int t = (int)(bid - NB_CONV);       // 0..767
    const int x = t >> 4, m = t & 15;         // x: 48 = p(3) x ktile(16)
    const int p = x >> 4, kt = x & 15;
    const void* src = (p==0) ? p1 : (p==1) ? p2 : p3;
    const int kr = tid >> 2, dc = (tid & 3) * 16;
    long off = ((long)m*H_ + kt*64 + kr)*D_ + dc;
    if(flag){
      const unsigned short* s = (const unsigned short*)src + off;
      *reinterpret_cast<uintx4*>(&Tb[kr*72+dc])   = *reinterpret_cast<const uintx4*>(s);
      *reinterpret_cast<uintx4*>(&Tb[kr*72+dc+8]) = *reinterpret_cast<const uintx4*>(s+8);
    } else {
      const float* f = (const float*)src + off;
      #pragma unroll
      for(int j=0;j<8;j++){
        unsigned int w = pk2bf(f[2*j], f[2*j+1]);
        *reinterpret_cast<unsigned int*>(&Tb[kr*72+dc+2*j]) = w;
      }
    }
    __syncthreads();
    const int dr = tid >> 2, kc = (tid & 3) * 16;
    uintx4 o0, o1;
    #pragma unroll
    for(int j=0;j<4;j++){
      o0[j] = (unsigned int)Tb[(kc+2*j  )*72+dr] | ((unsigned int)Tb[(kc+2*j+1)*72+dr]<<16);
      o1[j] = (unsigned int)Tb[(kc+8+2*j)*72+dr] | ((unsigned int)Tb[(kc+9+2*j)*72+dr]<<16);
    }
    unsigned short* dst = WT + ((long)(m*3+p)*D_ + dr)*H_ + kt*64 + kc;
    *reinterpret_cast<uintx4*>(dst)   = o0;
    *reinterpret_cast<uintx4*>(dst+8) = o1;
  }
}

// ---------------------------------------------------------------------------
// Kernel 1: q,k,v projections. 128 rows x 192 cols (one expert) per block.
// [R7 version verbatim — R8's dbuf+XCD-swizzle variant regressed ~3us.]
// Staging via global_load_lds (linear dest, pre-swizzled source col,
// (row&7)<<4 XOR read) -- m97 pattern. 40 KB LDS, 2 barriers/K-step.
// ---------------------------------------------------------------------------
__global__ __launch_bounds__(256) void qkv_kernel(
    const unsigned short* __restrict__ hid,
    const unsigned short* __restrict__ WT,
    unsigned short* __restrict__ qo,
    unsigned short* __restrict__ ko,
    unsigned short* __restrict__ vT)
{
  __shared__ __align__(16) char AbB[16384];   // A [128 t][128 B] swz
  __shared__ __align__(16) char WbB[24576];   // W [3 p][64 d][128 B] swz

  const int m  = blockIdx.y;
  const int r0 = blockIdx.x * 128;
  const int b  = r0 >> 11;
  const int tl = r0 & (T_-1);
  const int tid = threadIdx.x;
  const int lane = tid & 63, wid = tid >> 6;
  const int lc = lane & 15, qd = lane >> 4;
  const int kswz = (lc & 7) << 4;

  const char* hidB = (const char*)hid;
  const char* wtB  = (const char*)WT;

  // staging maps: instr (wid,i) writes 1KB linear LDS; lane covers chunk g
  long asrc[4];
  #pragma unroll
  for(int i=0;i<4;i++){
    int g = ((wid*4 + i)<<6) + lane;          // 0..1023 chunk of A tile
    int row = g >> 3, c = g & 7;
    asrc[i] = ((long)(r0 + row) << 11) + ((c<<4) ^ ((row&7)<<4));
  }
  long wsrc[6];
  #pragma unroll
  for(int i=0;i<6;i++){
    int g = ((wid*6 + i)<<6) + lane;          // 0..1535 chunk of W tiles
    int p = g >> 9, row = (g>>3) & 63, c = g & 7;
    long R = (long)(m*3 + p)*64 + row;
    wsrc[i] = (R << 11) + ((c<<4) ^ ((row&7)<<4));
  }

  floatx4 accq[4][2], acck[4][2], accv[4][2];
  #pragma unroll
  for(int nt=0;nt<4;nt++)
    #pragma unroll
    for(int ss=0;ss<2;ss++){ accq[nt][ss]=(floatx4)(0.f); acck[nt][ss]=(floatx4)(0.f); accv[nt][ss]=(floatx4)(0.f); }

  for(int kk=0; kk<H_; kk+=64){
    const long kb2 = (long)kk << 1;
    #pragma unroll
    for(int i=0;i<4;i++) gload16(hidB + asrc[i] + kb2, AbB + ((wid*4+i)<<10));
    #pragma unroll
    for(int i=0;i<6;i++) gload16(wtB  + wsrc[i] + kb2, WbB + ((wid*6+i)<<10));
    __syncthreads();                          // drains vmcnt before barrier
    #pragma unroll
    for(int kc=0;kc<2;kc++){
      const int cb = (kc*64 + qd*16) ^ kswz;
      bf16x8 a0 = *(const bf16x8*)(AbB + (wid*32      + lc)*128 + cb);
      bf16x8 a1 = *(const bf16x8*)(AbB + (wid*32 + 16 + lc)*128 + cb);
      #pragma unroll
      for(int nt=0;nt<4;nt++){
        bf16x8 bq = *(const bf16x8*)(WbB +         (nt*16+lc)*128 + cb);
        accq[nt][0] = __builtin_amdgcn_mfma_f32_16x16x32_bf16(a0, bq, accq[nt][0],0,0,0);
        accq[nt][1] = __builtin_amdgcn_mfma_f32_16x16x32_bf16(a1, bq, accq[nt][1],0,0,0);
        bf16x8 bk = *(const bf16x8*)(WbB + 8192 +  (nt*16+lc)*128 + cb);
        acck[nt][0] = __builtin_amdgcn_mfma_f32_16x16x32_bf16(a0, bk, acck[nt][0],0,0,0);
        acck[nt][1] = __builtin_amdgcn_mfma_f32_16x16x32_bf16(a1, bk, acck[nt][1],0,0,0);
        bf16x8 bv = *(const bf16x8*)(WbB + 16384 + (nt*16+lc)*128 + cb);
        accv[nt][0] = __builtin_amdgcn_mfma_f32_16x16x32_bf16(bv, a0, accv[nt][0],0,0,0);
        accv[nt][1] = __builtin_amdgcn_mfma_f32_16x16x32_bf16(bv, a1, accv[nt][1],0,0,0);
      }
    }
    __syncthreads();                          // protect LDS before next stage
  }

  const long obase = (long)(b*M_+m)*T_ + tl;
  #pragma unroll
  for(int nt=0;nt<4;nt++)
    #pragma unroll
    for(int ss=0;ss<2;ss++)
      #pragma unroll
      for(int r=0;r<4;r++){
        int trow = wid*32 + ss*16 + qd*4 + r;
        qo[(obase + trow)*D_ + nt*16 + lc] = f2bfn(accq[nt][ss][r]);
        ko[(obase + trow)*D_ + nt*16 + lc] = f2bfn(acck[nt][ss][r]);
      }
  const long vbase = (long)(b*M_+m)*D_;
  #pragma unroll
  for(int nt=0;nt<4;nt++)
    #pragma unroll
    for(int ss=0;ss<2;ss++)
      #pragma unroll
      for(int r=0;r<4;r++){
        int d    = nt*16 + qd*4 + r;
        int tcol = wid*32 + ss*16 + lc;
        vT[(vbase + d)*T_ + tl + tcol] = f2bfn(accv[nt][ss][r]);
      }
}

// ---------------------------------------------------------------------------
// Kernel 2: flash attention, 32x32 MFMA, 4 waves x 32 Q-rows, KVBLK=64.
// [R8 version] + 4-way partial lr/tr accumulators (break the 32-long serial
// fmaf dependency chains; ~256cy/round of dep-latency at 2 waves/SIMD).
// ---------------------------------------------------------------------------
__global__ __launch_bounds__(256, 2) void attn_kernel(
    const unsigned short* __restrict__ q,
    const unsigned short* __restrict__ k,
    const unsigned short* __restrict__ vT,
    unsigned short* __restrict__ shaC,
    void* __restrict__ out, const int* __restrict__ flagp,
    double* __restrict__ aff)
{
  // 48 KB: 3 bufs x { K [64 j][128 B] , V [64 d][128 B] }, swizzle (row&7)<<4
  __shared__ __align__(16) char Sm[3*16384];

  // XCD-aware bijective remap: lid&7 = XCD; each XCD gets bm in [xcd*4, +4)
  const int lid = blockIdx.y * 16 + blockIdx.x;   // [0,512)
  const int bm  = (lid & 7) * 4 + (lid >> 7);     // [0,32)
  const int qt  = (lid >> 3) & 15;                // [0,16)
  const int b = bm >> 4, m = bm & 15;
  const int tid = threadIdx.x;
  const int lane = tid & 63, wid = tid >> 6;  // 4 waves x 32 q-rows
  const int il = lane & 31, hi = lane >> 5;

  const char* kp8 = (const char*)(k  + (long)bm*T_*D_);
  const char* vp8 = (const char*)(vT + (long)bm*D_*T_);
  const unsigned short* qp = q + (long)(bm*T_ + qt*128 + wid*32)*D_;

  // Q B-fragments (col = q-row il, k = d): 4 chunks of 16 d
  bf16x8 qf0 = *(const bf16x8*)&qp[(long)il*64 +  0 + hi*8];
  bf16x8 qf1 = *(const bf16x8*)&qp[(long)il*64 + 16 + hi*8];
  bf16x8 qf2 = *(const bf16x8*)&qp[(long)il*64 + 32 + hi*8];
  bf16x8 qf3 = *(const bf16x8*)&qp[(long)il*64 + 48 + hi*8];

  floatx16 oa0 = (floatx16)(0.f), oa1 = (floatx16)(0.f);
  double ldd = 0.0, tdd = 0.0;
  const float C2 = 0.1803368801f;             // 0.125 * log2(e)

  // staging constants: lane covers row (lane>>3), 16B col (lane&7)
  const int srow = lane >> 3;                 // 0..7
  const int scs  = ((lane & 7) * 16) ^ (srow << 4);  // pre-swizzled source col
  const char* ksrc0 = kp8 + (long)(wid*16 + srow)*128  + scs;
  const char* vsrc0 = vp8 + (long)(wid*16 + srow)*4096 + scs;
  const int kswz = (il & 7) << 4;             // read swizzle ((row&7)<<4)
  char* SmB = (char*)Sm;

  // stage round r (64 j x 128B K, 64 d x 128B V) into buffer s
  #define STAGE(r, s) { \
    char* kd = SmB + (s)*16384 + wid*2048; \
    gload16(ksrc0 + (long)(r)*8192,        kd); \
    gload16(ksrc0 + (long)(r)*8192 + 1024, kd + 1024); \
    char* vd = SmB + (s)*16384 + 8192 + wid*2048; \
    gload16(vsrc0 + (r)*128,               vd); \
    gload16(vsrc0 + 8*4096 + (r)*128,      vd + 1024); \
  }
  #define WAITV4() asm volatile("s_waitcnt vmcnt(4)" ::: "memory")
  #define WAITV0() asm volatile("s_waitcnt vmcnt(0)" ::: "memory")
  #define BAR() { __builtin_amdgcn_s_barrier(); __builtin_amdgcn_sched_barrier(0); }

  auto compute = [&](const int s){
    const char* Kb = SmB + s*16384;
    const char* Vb = SmB + s*16384 + 8192;
    float lr0=0.f, lr1=0.f, lr2=0.f, lr3=0.f;
    float tr0=0.f, tr1=0.f, tr2=0.f, tr3=0.f;
    #pragma unroll
    for(int jt=0; jt<2; jt++){
      const char* krow = Kb + (jt*32 + il)*128;
      floatx16 sa = (floatx16)(0.f);
      bf16x8 kf0 = *(const bf16x8*)(krow + (( 0 + 16*hi) ^ kswz));
      bf16x8 kf1 = *(const bf16x8*)(krow + ((32 + 16*hi) ^ kswz));
      bf16x8 kf2 = *(const bf16x8*)(krow + ((64 + 16*hi) ^ kswz));
      bf16x8 kf3 = *(const bf16x8*)(krow + ((96 + 16*hi) ^ kswz));
      __builtin_amdgcn_s_setprio(1);
      sa = __builtin_amdgcn_mfma_f32_32x32x16_bf16(kf0, qf0, sa, 0,0,0);
      sa = __builtin_amdgcn_mfma_f32_32x32x16_bf16(kf1, qf1, sa, 0,0,0);
      sa = __builtin_amdgcn_mfma_f32_32x32x16_bf16(kf2, qf2, sa, 0,0,0);
      sa = __builtin_amdgcn_mfma_f32_32x32x16_bf16(kf3, qf3, sa, 0,0,0);
      __builtin_amdgcn_s_setprio(0);
      // sa[e] = S[j = (e&3)+8*(e>>2)+4*hi + jt*32][i = il]
      float p[16];
      #pragma unroll
      for(int e=0; e<16; e+=4){
        float v0 = __builtin_amdgcn_exp2f(sa[e+0]*C2);  // exp(0.125*s)
        float v1 = __builtin_amdgcn_exp2f(sa[e+1]*C2);
        float v2 = __builtin_amdgcn_exp2f(sa[e+2]*C2);
        float v3 = __builtin_amdgcn_exp2f(sa[e+3]*C2);
        p[e+0]=v0; p[e+1]=v1; p[e+2]=v2; p[e+3]=v3;
        lr0 += v0; lr1 += v1; lr2 += v2; lr3 += v3;
        tr0 = fmaf(v0, sa[e+0], tr0);
        tr1 = fmaf(v1, sa[e+1], tr1);
        tr2 = fmaf(v2, sa[e+2], tr2);
        tr3 = fmaf(v3, sa[e+3], tr3);
      }
      #pragma unroll
      for(int jc=0; jc<2; jc++){
        // pack own j {0..3,8..11} halves; swap with lane^32 for {4..7,12..15}
        unsigned int w0 = pk2bf(p[jc*8+0], p[jc*8+1]);
        unsigned int w1 = pk2bf(p[jc*8+2], p[jc*8+3]);
        unsigned int w2 = pk2bf(p[jc*8+4], p[jc*8+5]);
        unsigned int w3 = pk2bf(p[jc*8+6], p[jc*8+7]);
        pl32swap(w0, w2);
        pl32swap(w1, w3);
        uintx4 aw; aw[0]=w0; aw[1]=w1; aw[2]=w2; aw[3]=w3;
        bf16x8 ap = __builtin_bit_cast(bf16x8, aw);
        const int jb = jt*64 + jc*32 + 16*hi;   // byte col of k-slice in V rows
        bf16x8 vf0 = *(const bf16x8*)(Vb + (     il)*128 + (jb ^ kswz));
        bf16x8 vf1 = *(const bf16x8*)(Vb + (32 + il)*128 + (jb ^ kswz));
        __builtin_amdgcn_s_setprio(1);
        oa0 = __builtin_amdgcn_mfma_f32_32x32x16_bf16(ap, vf0, oa0, 0,0,0);
        oa1 = __builtin_amdgcn_mfma_f32_32x32x16_bf16(ap, vf1, oa1, 0,0,0);
        __builtin_amdgcn_s_setprio(0);
      }
    }
    ldd += (double)((lr0+lr1)+(lr2+lr3));
    tdd += (double)((tr0+tr1)+(tr2+tr3));
  };

  STAGE(0, 0);
  STAGE(1, 1);
  for(int rr=0; rr<30; rr+=3){
    WAITV4(); BAR(); STAGE(rr+2, 2); compute(0);
    WAITV4(); BAR(); STAGE(rr+3, 0); compute(1);
    WAITV4(); BAR(); STAGE(rr+4, 1); compute(2);
  }
  WAITV0(); BAR();
  compute(0);                                  // round 30
  compute(1);                                  // round 31

  // ---- epilogue: per-wave, lane il holds l/t for q-row il (both halves) ----
  ldd += __shfl_xor(ldd, 32); tdd += __shfl_xor(tdd, 32);
  double es = log(ldd) - 0.125*(tdd/ldd);
  es += __shfl_xor(es,1); es += __shfl_xor(es,2);
  es += __shfl_xor(es,4); es += __shfl_xor(es,8); es += __shfl_xor(es,16);
  if(lane == 0) atomicAdd(&aff[bm], es);

  const int flag = *flagp;
  float lf = (float)ldd;
  #pragma unroll
  for(int r=0;r<16;r++){
    const int row = (r&3) + 8*(r>>2) + 4*hi;
    float linv = 1.0f / __shfl(lf, row);
    const int trow_ = qt*128 + wid*32 + row;
    float sv0 = oa0[r] * linv;
    float sv1 = oa1[r] * linv;
    long idx0 = ((long)(b*T_ + trow_)*M_ + m)*D_ + il;
    shaC[idx0]      = f2bfn(sv0);
    shaC[idx0 + 32] = f2bfn(sv1);
    store_out(out, flag, OUT_SHA + idx0,      sv0);
    store_out(out, flag, OUT_SHA + idx0 + 32, sv1);
  }
  #undef STAGE
  #undef WAITV4
  #undef WAITV0
  #undef BAR
}

// ---------------------------------------------------------------------------
// Kernel 4: fused gate + oproj. Lanes 0-31 of every block recompute the fp64
// gate math; block 0 writes gate outputs + nmask for final. Then
// dynO[b,d,h] = sum_m nm[b,m]*o_w[m,d,h] as before.
// ---------------------------------------------------------------------------
__global__ __launch_bounds__(256) void oproj_kernel(
    const unsigned short* __restrict__ ow, const double* __restrict__ aff_sum,
    const unsigned short* __restrict__ gates, void* __restrict__ out,
    const int* __restrict__ flagp, float* __restrict__ nmask_ws,
    float* __restrict__ dynO)
{
  __shared__ float nmL[32];
  const int tid = threadIdx.x;
  const int flag = *flagp;

  if(tid < 32){
    const int b = tid >> 4, mm = tid & 15;
    double a = -aff_sum[tid] / (double)T_;
    double s = a;
    s += __shfl_xor(s,1); s += __shfl_xor(s,2); s += __shfl_xor(s,4); s += __shfl_xor(s,8);
    double mu = s / 16.0;
    double dd = a - mu;
    double v = dd*dd;
    v += __shfl_xor(v,1); v += __shfl_xor(v,2); v += __shfl_xor(v,4); v += __shfl_xor(v,8);
    double sd = sqrt(v / 15.0);
    double z = dd / (sd + 1e-9);
    double g = (double)bf2f(gates[mm]);
    double pre = z - 1.0/(1.0 + exp(-g));

    int act = (pre > 0.0);
    unsigned long long bal = __ballot(act);
    int nact = __popcll((bal >> (b*16)) & 0xFFFFull);

    double mask;
    if(nact > 0){
      mask = act ? 1.0 : 0.0;
    } else {
      double m1 = z, m2 = -1e300;
      #pragma unroll
      for(int d2=1; d2<16; d2<<=1){
        double o1 = __shfl_xor(m1, d2), o2 = __shfl_xor(m2, d2);
        if(o1 > m1){ m2 = fmax(m1, o2); m1 = o1; }
        else       { m2 = fmax(m2, o1); }
      }
      mask = (z >= m2) ? 1.0 : 0.0;
    }
    int nsel = (nact > 0) ? nact : 2;
    float nmv = (float)(mask / (double)nsel);
    nmL[tid] = nmv;
    if(blockIdx.x == 0){
      store_out(out, flag, OUT_LOG  + tid, (float)pre);
      store_out(out, flag, OUT_MASK + tid, (float)mask);
      nmask_ws[tid] = nmv;
      unsigned long long fb = __ballot((nact==0) && (mm==0));
      if(tid == 0) store_out(out, flag, OUT_FBC, (float)__popcll(fb));
    }
  }
  __syncthreads();

  int idx = blockIdx.x*256 + tid;
  int b = idx >> 16;
  int dh = idx & 65535;
  float acc = 0.f;
  #pragma unroll
  for(int m=0;m<M_;m++) acc += nmL[b*M_+m]*bf2f(ow[m*D_*H_ + dh]);
  dynO[idx] = acc;
}

// ---------------------------------------------------------------------------
// Kernel 5: combined = sum_m nm*sha; final = combined x dynO.
// ---------------------------------------------------------------------------
__global__ __launch_bounds__(256) void final_kernel(
    const unsigned short* __restrict__ shaC, const float* __restrict__ nmask,
    const float* __restrict__ dynO, void* __restrict__ out,
    const int* __restrict__ flagp)
{
  __shared__ float combT[64][36];       // [d][tt], padded
  const int bx = blockIdx.x;            // 128 = b(2) x ttile(64)
  const int b  = bx >> 6;
  const int t0 = (bx & 63) * 32;
  const int h  = blockIdx.y*256 + threadIdx.x;
  const int tid = threadIdx.x;

  float nm[M_];
  #pragma unroll
  for(int m=0;m<M_;m++) nm[m] = nmask[b*M_+m];

  #pragma unroll
  for(int pass=0;pass<8;pass++){
    int idx = pass*256 + tid;
    int d = idx & 63, tt = idx >> 6;
    const unsigned short* sp = shaC + ((long)(b*T_ + t0 + tt)*M_)*D_ + d;
    float a = 0.f;
    #pragma unroll
    for(int m=0;m<M_;m++) a = fmaf(nm[m], bf2f(sp[m*D_]), a);
    combT[d][tt] = a;
  }
  __syncthreads();

  float acc[32];
  #pragma unroll
  for(int tt=0;tt<32;tt++) acc[tt] = 0.f;
  for(int d=0; d<64; d++){
    float g = dynO[((long)b*D_ + d)*H_ + h];
    const floatx4* cp = reinterpret_cast<const floatx4*>(&combT[d][0]);
    #pragma unroll
    for(int c8=0;c8<8;c8++){
      floatx4 cv = cp[c8];
      #pragma unroll
      for(int r=0;r<4;r++) acc[c8*4+r] = fmaf(cv[r], g, acc[c8*4+r]);
    }
  }
  const int flag = *flagp;
  #pragma unroll
  for(int tt=0;tt<32;tt++)
    store_out(out, flag, (long)(b*T_ + t0 + tt)*H_ + h, acc[tt]);
}

// ---------------------------------------------------------------------------
extern "C" void kernel_launch(void* const* d_in, const int* in_sizes, int n_in,
                              void* d_out, int out_size, void* d_ws, size_t ws_size,
                              hipStream_t stream)
{
  (void)in_sizes; (void)n_in; (void)out_size; (void)ws_size;
  char* ws = (char*)d_ws;
  int*    flag  = (int*)(ws);
  double* aff   = (double*)(ws + 64);
  float*  nmask = (float*)(ws + 512);
  float*  dynO  = (float*)(ws + 4096);                        // 512 KB
  unsigned short* canon = (unsigned short*)(ws + (1u<<20));
  unsigned short* c_hid = canon;
  unsigned short* c_ow  = c_hid + N_HID;
  unsigned short* c_gt  = c_ow + N_OW;
  unsigned short* WT    = (unsigned short*)(ws + (size_t)12*1024*1024);
  unsigned short* qb    = (unsigned short*)(ws + (size_t)18*1024*1024);
  unsigned short* kb    = qb + (size_t)B_*M_*T_*D_;
  unsigned short* vT    = kb + (size_t)B_*M_*T_*D_;
  unsigned short* shaC  = vT + (size_t)B_*M_*T_*D_;

  prep_kernel   <<<NB_CONV + 768, 256, 0, stream>>>(
      d_in[0], d_in[1], d_in[2], d_in[3], d_in[4], d_in[5], canon, WT, flag, aff);
  qkv_kernel    <<<dim3(BT_/128, M_),256, 0, stream>>>(c_hid, WT, qb, kb, vT);
  attn_kernel   <<<dim3(T_/128, B_*M_),256,0, stream>>>(qb, kb, vT, shaC, d_out, flag, aff);
  oproj_kernel  <<<512, 256, 0, stream>>>(c_ow, aff, c_gt, d_out, flag, nmask, dynO);
  final_kernel  <<<dim3(128, 4), 256, 0, stream>>>(shaC, nmask, dynO, d_out, flag);
}

// Round 10
// 198.426 us; speedup vs baseline: 1.0117x; 1.0117x over previous
//
#include <hip/hip_runtime.h>

#define B_ 2
#define T_ 2048
#define H_ 1024
#define D_ 64
#define M_ 16
#define BT_ (B_*T_)

#define N_HID (B_*T_*H_)          // 4194304
#define N_W   (M_*H_*D_)          // 1048576
#define N_OW  (M_*D_*H_)          // 1048576
#define N_C   (N_HID + N_OW + 16) // canon: hid + ow + gates
#define NB_CONV 5121              // (N_C/4 + 255)/256

#define OUT_SHA  (B_*T_*H_)       // 4194304
#define OUT_LOG  (2*B_*T_*H_)     // 8388608
#define OUT_MASK (OUT_LOG + B_*M_)
#define OUT_FBC  (OUT_MASK + B_*M_)

typedef __bf16 bf16x8 __attribute__((ext_vector_type(8)));
typedef float floatx4 __attribute__((ext_vector_type(4)));
typedef float floatx16 __attribute__((ext_vector_type(16)));
typedef unsigned int uintx4 __attribute__((ext_vector_type(4)));

__device__ __forceinline__ float bf2f(unsigned short u){
  unsigned int v = ((unsigned int)u) << 16;
  return __builtin_bit_cast(float, v);
}
__device__ __forceinline__ unsigned short f2bfn(float f){
  __bf16 h = (__bf16)f;                       // RNE
  return __builtin_bit_cast(unsigned short, h);
}
__device__ __forceinline__ unsigned int pk2bf(float a, float b){
  return (unsigned int)f2bfn(a) | ((unsigned int)f2bfn(b) << 16);
}
__device__ __forceinline__ void store_out(void* out, int flag, long idx, float v){
  if(flag) ((unsigned short*)out)[idx] = f2bfn(v);
  else     ((float*)out)[idx] = v;
}
__device__ __forceinline__ void gload16(const void* g, void* l){
  __builtin_amdgcn_global_load_lds(
      (const __attribute__((address_space(1))) unsigned int*)g,
      (__attribute__((address_space(3))) unsigned int*)l, 16, 0, 0);
}
// v_permlane32_swap_b32: a.hi <-> b.lo (register-only, data deps via +v)
__device__ __forceinline__ void pl32swap(unsigned int &a, unsigned int &b){
  asm("v_permlane32_swap_b32 %0, %1" : "+v"(a), "+v"(b));
}

// ---------------------------------------------------------------------------
// Kernel P: fused prep = detect + convert + wtrans.
// ---------------------------------------------------------------------------
__global__ __launch_bounds__(256) void prep_kernel(
    const void* __restrict__ p0, const void* __restrict__ p1,
    const void* __restrict__ p2, const void* __restrict__ p3,
    const void* __restrict__ p4, const void* __restrict__ p5,
    unsigned short* __restrict__ canon, unsigned short* __restrict__ WT,
    int* __restrict__ flag_ws, double* __restrict__ aff)
{
  __shared__ int red[4];
  __shared__ __align__(16) unsigned short Tb[64*72];
  const int tid = threadIdx.x;
  const long bid = blockIdx.x;

  // ---- per-block dtype detect ----
  {
    const unsigned int* hw = (const unsigned int*)p0;
    int c = 0;
    #pragma unroll
    for(int i=0;i<4;i++){
      unsigned int e = (hw[tid + i*256] >> 7) & 0xFFu;
      c += (e >= 96u && e <= 144u);
    }
    c += __shfl_xor(c,1); c += __shfl_xor(c,2); c += __shfl_xor(c,4);
    c += __shfl_xor(c,8); c += __shfl_xor(c,16); c += __shfl_xor(c,32);
    if((tid & 63) == 0) red[tid >> 6] = c;
  }
  __syncthreads();
  const int flag = (red[0]+red[1]+red[2]+red[3] > 512) ? 1 : 0;

  if(bid == 0){
    if(tid == 0) *flag_ws = flag;
    if(tid < B_*M_) aff[tid] = 0.0;
  }

  if(bid < NB_CONV){
    // ---- convert role ----
    long i4 = (bid*256 + tid) * 4;
    if(i4 >= N_C) return;
    const void* src; long off;
    if(i4 < N_HID)            { src=p0; off=i4; }
    else if(i4 < N_HID+N_OW)  { src=p4; off=i4-N_HID; }
    else                      { src=p5; off=i4-N_HID-N_OW; }
    unsigned long long r;
    if(flag){
      r = *reinterpret_cast<const unsigned long long*>((const unsigned short*)src + off);
    } else {
      const float* f = (const float*)src + off;
      unsigned long long a = f2bfn(f[0]), b = f2bfn(f[1]), c = f2bfn(f[2]), d = f2bfn(f[3]);
      r = a | (b<<16) | (c<<32) | (d<<48);
    }
    *reinterpret_cast<unsigned long long*>(canon + i4) = r;
  } else {
    // ---- wtrans role ----
    const int t = (int)(bid - NB_CONV);       // 0..767
    const int x = t >> 4, m = t & 15;         // x: 48 = p(3) x ktile(16)
    const int p = x >> 4, kt = x & 15;
    const void* src = (p==0) ? p1 : (p==1) ? p2 : p3;
    const int kr = tid >> 2, dc = (tid & 3) * 16;
    long off = ((long)m*H_ + kt*64 + kr)*D_ + dc;
    if(flag){
      const unsigned short* s = (const unsigned short*)src + off;
      *reinterpret_cast<uintx4*>(&Tb[kr*72+dc])   = *reinterpret_cast<const uintx4*>(s);
      *reinterpret_cast<uintx4*>(&Tb[kr*72+dc+8]) = *reinterpret_cast<const uintx4*>(s+8);
    } else {
      const float* f = (const float*)src + off;
      #pragma unroll
      for(int j=0;j<8;j++){
        unsigned int w = pk2bf(f[2*j], f[2*j+1]);
        *reinterpret_cast<unsigned int*>(&Tb[kr*72+dc+2*j]) = w;
      }
    }
    __syncthreads();
    const int dr = tid >> 2, kc = (tid & 3) * 16;
    uintx4 o0, o1;
    #pragma unroll
    for(int j=0;j<4;j++){
      o0[j] = (unsigned int)Tb[(kc+2*j  )*72+dr] | ((unsigned int)Tb[(kc+2*j+1)*72+dr]<<16);
      o1[j] = (unsigned int)Tb[(kc+8+2*j)*72+dr] | ((unsigned int)Tb[(kc+9+2*j)*72+dr]<<16);
    }
    unsigned short* dst = WT + ((long)(m*3+p)*D_ + dr)*H_ + kt*64 + kc;
    *reinterpret_cast<uintx4*>(dst)   = o0;
    *reinterpret_cast<uintx4*>(dst+8) = o1;
  }
}

// ---------------------------------------------------------------------------
// Kernel 1: q,k,v projections. 128 rows x 192 cols (one expert) per block.
// [R7 version verbatim — proven best: R8's dbuf+XCD-swizzle regressed ~3.7us.]
// Staging via global_load_lds (linear dest, pre-swizzled source col,
// (row&7)<<4 XOR read) -- m97 pattern. 40 KB LDS, 2 barriers/K-step.
// ---------------------------------------------------------------------------
__global__ __launch_bounds__(256) void qkv_kernel(
    const unsigned short* __restrict__ hid,
    const unsigned short* __restrict__ WT,
    unsigned short* __restrict__ qo,
    unsigned short* __restrict__ ko,
    unsigned short* __restrict__ vT)
{
  __shared__ __align__(16) char AbB[16384];   // A [128 t][128 B] swz
  __shared__ __align__(16) char WbB[24576];   // W [3 p][64 d][128 B] swz

  const int m  = blockIdx.y;
  const int r0 = blockIdx.x * 128;
  const int b  = r0 >> 11;
  const int tl = r0 & (T_-1);
  const int tid = threadIdx.x;
  const int lane = tid & 63, wid = tid >> 6;
  const int lc = lane & 15, qd = lane >> 4;
  const int kswz = (lc & 7) << 4;

  const char* hidB = (const char*)hid;
  const char* wtB  = (const char*)WT;

  // staging maps: instr (wid,i) writes 1KB linear LDS; lane covers chunk g
  long asrc[4];
  #pragma unroll
  for(int i=0;i<4;i++){
    int g = ((wid*4 + i)<<6) + lane;          // 0..1023 chunk of A tile
    int row = g >> 3, c = g & 7;
    asrc[i] = ((long)(r0 + row) << 11) + ((c<<4) ^ ((row&7)<<4));
  }
  long wsrc[6];
  #pragma unroll
  for(int i=0;i<6;i++){
    int g = ((wid*6 + i)<<6) + lane;          // 0..1535 chunk of W tiles
    int p = g >> 9, row = (g>>3) & 63, c = g & 7;
    long R = (long)(m*3 + p)*64 + row;
    wsrc[i] = (R << 11) + ((c<<4) ^ ((row&7)<<4));
  }

  floatx4 accq[4][2], acck[4][2], accv[4][2];
  #pragma unroll
  for(int nt=0;nt<4;nt++)
    #pragma unroll
    for(int ss=0;ss<2;ss++){ accq[nt][ss]=(floatx4)(0.f); acck[nt][ss]=(floatx4)(0.f); accv[nt][ss]=(floatx4)(0.f); }

  for(int kk=0; kk<H_; kk+=64){
    const long kb2 = (long)kk << 1;
    #pragma unroll
    for(int i=0;i<4;i++) gload16(hidB + asrc[i] + kb2, AbB + ((wid*4+i)<<10));
    #pragma unroll
    for(int i=0;i<6;i++) gload16(wtB  + wsrc[i] + kb2, WbB + ((wid*6+i)<<10));
    __syncthreads();                          // drains vmcnt before barrier
    #pragma unroll
    for(int kc=0;kc<2;kc++){
      const int cb = (kc*64 + qd*16) ^ kswz;
      bf16x8 a0 = *(const bf16x8*)(AbB + (wid*32      + lc)*128 + cb);
      bf16x8 a1 = *(const bf16x8*)(AbB + (wid*32 + 16 + lc)*128 + cb);
      #pragma unroll
      for(int nt=0;nt<4;nt++){
        bf16x8 bq = *(const bf16x8*)(WbB +         (nt*16+lc)*128 + cb);
        accq[nt][0] = __builtin_amdgcn_mfma_f32_16x16x32_bf16(a0, bq, accq[nt][0],0,0,0);
        accq[nt][1] = __builtin_amdgcn_mfma_f32_16x16x32_bf16(a1, bq, accq[nt][1],0,0,0);
        bf16x8 bk = *(const bf16x8*)(WbB + 8192 +  (nt*16+lc)*128 + cb);
        acck[nt][0] = __builtin_amdgcn_mfma_f32_16x16x32_bf16(a0, bk, acck[nt][0],0,0,0);
        acck[nt][1] = __builtin_amdgcn_mfma_f32_16x16x32_bf16(a1, bk, acck[nt][1],0,0,0);
        bf16x8 bv = *(const bf16x8*)(WbB + 16384 + (nt*16+lc)*128 + cb);
        accv[nt][0] = __builtin_amdgcn_mfma_f32_16x16x32_bf16(bv, a0, accv[nt][0],0,0,0);
        accv[nt][1] = __builtin_amdgcn_mfma_f32_16x16x32_bf16(bv, a1, accv[nt][1],0,0,0);
      }
    }
    __syncthreads();                          // protect LDS before next stage
  }

  const long obase = (long)(b*M_+m)*T_ + tl;
  #pragma unroll
  for(int nt=0;nt<4;nt++)
    #pragma unroll
    for(int ss=0;ss<2;ss++)
      #pragma unroll
      for(int r=0;r<4;r++){
        int trow = wid*32 + ss*16 + qd*4 + r;
        qo[(obase + trow)*D_ + nt*16 + lc] = f2bfn(accq[nt][ss][r]);
        ko[(obase + trow)*D_ + nt*16 + lc] = f2bfn(acck[nt][ss][r]);
      }
  const long vbase = (long)(b*M_+m)*D_;
  #pragma unroll
  for(int nt=0;nt<4;nt++)
    #pragma unroll
    for(int ss=0;ss<2;ss++)
      #pragma unroll
      for(int r=0;r<4;r++){
        int d    = nt*16 + qd*4 + r;
        int tcol = wid*32 + ss*16 + lc;
        vT[(vbase + d)*T_ + tl + tcol] = f2bfn(accv[nt][ss][r]);
      }
}

// ---------------------------------------------------------------------------
// Kernel 2: flash attention, 32x32 MFMA, 4 waves x 32 Q-rows, KVBLK=64.
// [R8 version verbatim, 62.0us measured — single lr/tr chains (R9's 4-way
// partials regressed +5.4us); XCD-aware bm swizzle (FETCH 69.8->12.4 MB).]
// ---------------------------------------------------------------------------
__global__ __launch_bounds__(256, 2) void attn_kernel(
    const unsigned short* __restrict__ q,
    const unsigned short* __restrict__ k,
    const unsigned short* __restrict__ vT,
    unsigned short* __restrict__ shaC,
    void* __restrict__ out, const int* __restrict__ flagp,
    double* __restrict__ aff)
{
  // 48 KB: 3 bufs x { K [64 j][128 B] , V [64 d][128 B] }, swizzle (row&7)<<4
  __shared__ __align__(16) char Sm[3*16384];

  // XCD-aware bijective remap: lid&7 = XCD; each XCD gets bm in [xcd*4, +4)
  const int lid = blockIdx.y * 16 + blockIdx.x;   // [0,512)
  const int bm  = (lid & 7) * 4 + (lid >> 7);     // [0,32)
  const int qt  = (lid >> 3) & 15;                // [0,16)
  const int b = bm >> 4, m = bm & 15;
  const int tid = threadIdx.x;
  const int lane = tid & 63, wid = tid >> 6;  // 4 waves x 32 q-rows
  const int il = lane & 31, hi = lane >> 5;

  const char* kp8 = (const char*)(k  + (long)bm*T_*D_);
  const char* vp8 = (const char*)(vT + (long)bm*D_*T_);
  const unsigned short* qp = q + (long)(bm*T_ + qt*128 + wid*32)*D_;

  // Q B-fragments (col = q-row il, k = d): 4 chunks of 16 d
  bf16x8 qf0 = *(const bf16x8*)&qp[(long)il*64 +  0 + hi*8];
  bf16x8 qf1 = *(const bf16x8*)&qp[(long)il*64 + 16 + hi*8];
  bf16x8 qf2 = *(const bf16x8*)&qp[(long)il*64 + 32 + hi*8];
  bf16x8 qf3 = *(const bf16x8*)&qp[(long)il*64 + 48 + hi*8];

  floatx16 oa0 = (floatx16)(0.f), oa1 = (floatx16)(0.f);
  double ldd = 0.0, tdd = 0.0;
  const float C2 = 0.1803368801f;             // 0.125 * log2(e)

  // staging constants: lane covers row (lane>>3), 16B col (lane&7)
  const int srow = lane >> 3;                 // 0..7
  const int scs  = ((lane & 7) * 16) ^ (srow << 4);  // pre-swizzled source col
  const char* ksrc0 = kp8 + (long)(wid*16 + srow)*128  + scs;
  const char* vsrc0 = vp8 + (long)(wid*16 + srow)*4096 + scs;
  const int kswz = (il & 7) << 4;             // read swizzle ((row&7)<<4)
  char* SmB = (char*)Sm;

  // stage round r (64 j x 128B K, 64 d x 128B V) into buffer s
  #define STAGE(r, s) { \
    char* kd = SmB + (s)*16384 + wid*2048; \
    gload16(ksrc0 + (long)(r)*8192,        kd); \
    gload16(ksrc0 + (long)(r)*8192 + 1024, kd + 1024); \
    char* vd = SmB + (s)*16384 + 8192 + wid*2048; \
    gload16(vsrc0 + (r)*128,               vd); \
    gload16(vsrc0 + 8*4096 + (r)*128,      vd + 1024); \
  }
  #define WAITV4() asm volatile("s_waitcnt vmcnt(4)" ::: "memory")
  #define WAITV0() asm volatile("s_waitcnt vmcnt(0)" ::: "memory")
  #define BAR() { __builtin_amdgcn_s_barrier(); __builtin_amdgcn_sched_barrier(0); }

  auto compute = [&](const int s){
    const char* Kb = SmB + s*16384;
    const char* Vb = SmB + s*16384 + 8192;
    float lr = 0.f, tr = 0.f;
    #pragma unroll
    for(int jt=0; jt<2; jt++){
      const char* krow = Kb + (jt*32 + il)*128;
      floatx16 sa = (floatx16)(0.f);
      bf16x8 kf0 = *(const bf16x8*)(krow + (( 0 + 16*hi) ^ kswz));
      bf16x8 kf1 = *(const bf16x8*)(krow + ((32 + 16*hi) ^ kswz));
      bf16x8 kf2 = *(const bf16x8*)(krow + ((64 + 16*hi) ^ kswz));
      bf16x8 kf3 = *(const bf16x8*)(krow + ((96 + 16*hi) ^ kswz));
      __builtin_amdgcn_s_setprio(1);
      sa = __builtin_amdgcn_mfma_f32_32x32x16_bf16(kf0, qf0, sa, 0,0,0);
      sa = __builtin_amdgcn_mfma_f32_32x32x16_bf16(kf1, qf1, sa, 0,0,0);
      sa = __builtin_amdgcn_mfma_f32_32x32x16_bf16(kf2, qf2, sa, 0,0,0);
      sa = __builtin_amdgcn_mfma_f32_32x32x16_bf16(kf3, qf3, sa, 0,0,0);
      __builtin_amdgcn_s_setprio(0);
      // sa[e] = S[j = (e&3)+8*(e>>2)+4*hi + jt*32][i = il]
      float p[16];
      #pragma unroll
      for(int e=0; e<16; e++){
        float v = __builtin_amdgcn_exp2f(sa[e]*C2);   // exp(0.125*s)
        p[e] = v; lr += v; tr = fmaf(v, sa[e], tr);
      }
      #pragma unroll
      for(int jc=0; jc<2; jc++){
        // pack own j {0..3,8..11} halves; swap with lane^32 for {4..7,12..15}
        unsigned int w0 = pk2bf(p[jc*8+0], p[jc*8+1]);
        unsigned int w1 = pk2bf(p[jc*8+2], p[jc*8+3]);
        unsigned int w2 = pk2bf(p[jc*8+4], p[jc*8+5]);
        unsigned int w3 = pk2bf(p[jc*8+6], p[jc*8+7]);
        pl32swap(w0, w2);
        pl32swap(w1, w3);
        uintx4 aw; aw[0]=w0; aw[1]=w1; aw[2]=w2; aw[3]=w3;
        bf16x8 ap = __builtin_bit_cast(bf16x8, aw);
        const int jb = jt*64 + jc*32 + 16*hi;   // byte col of k-slice in V rows
        bf16x8 vf0 = *(const bf16x8*)(Vb + (     il)*128 + (jb ^ kswz));
        bf16x8 vf1 = *(const bf16x8*)(Vb + (32 + il)*128 + (jb ^ kswz));
        __builtin_amdgcn_s_setprio(1);
        oa0 = __builtin_amdgcn_mfma_f32_32x32x16_bf16(ap, vf0, oa0, 0,0,0);
        oa1 = __builtin_amdgcn_mfma_f32_32x32x16_bf16(ap, vf1, oa1, 0,0,0);
        __builtin_amdgcn_s_setprio(0);
      }
    }
    ldd += (double)lr; tdd += (double)tr;
  };

  STAGE(0, 0);
  STAGE(1, 1);
  for(int rr=0; rr<30; rr+=3){
    WAITV4(); BAR(); STAGE(rr+2, 2); compute(0);
    WAITV4(); BAR(); STAGE(rr+3, 0); compute(1);
    WAITV4(); BAR(); STAGE(rr+4, 1); compute(2);
  }
  WAITV0(); BAR();
  compute(0);                                  // round 30
  compute(1);                                  // round 31

  // ---- epilogue: per-wave, lane il holds l/t for q-row il (both halves) ----
  ldd += __shfl_xor(ldd, 32); tdd += __shfl_xor(tdd, 32);
  double es = log(ldd) - 0.125*(tdd/ldd);
  es += __shfl_xor(es,1); es += __shfl_xor(es,2);
  es += __shfl_xor(es,4); es += __shfl_xor(es,8); es += __shfl_xor(es,16);
  if(lane == 0) atomicAdd(&aff[bm], es);

  const int flag = *flagp;
  float lf = (float)ldd;
  #pragma unroll
  for(int r=0;r<16;r++){
    const int row = (r&3) + 8*(r>>2) + 4*hi;
    float linv = 1.0f / __shfl(lf, row);
    const int trow_ = qt*128 + wid*32 + row;
    float sv0 = oa0[r] * linv;
    float sv1 = oa1[r] * linv;
    long idx0 = ((long)(b*T_ + trow_)*M_ + m)*D_ + il;
    shaC[idx0]      = f2bfn(sv0);
    shaC[idx0 + 32] = f2bfn(sv1);
    store_out(out, flag, OUT_SHA + idx0,      sv0);
    store_out(out, flag, OUT_SHA + idx0 + 32, sv1);
  }
  #undef STAGE
  #undef WAITV4
  #undef WAITV0
  #undef BAR
}

// ---------------------------------------------------------------------------
// Kernel 4: fused gate + oproj. Lanes 0-31 of every block recompute the fp64
// gate math; block 0 writes gate outputs + nmask for final. Then
// dynO[b,d,h] = sum_m nm[b,m]*o_w[m,d,h] as before.
// ---------------------------------------------------------------------------
__global__ __launch_bounds__(256) void oproj_kernel(
    const unsigned short* __restrict__ ow, const double* __restrict__ aff_sum,
    const unsigned short* __restrict__ gates, void* __restrict__ out,
    const int* __restrict__ flagp, float* __restrict__ nmask_ws,
    float* __restrict__ dynO)
{
  __shared__ float nmL[32];
  const int tid = threadIdx.x;
  const int flag = *flagp;

  if(tid < 32){
    const int b = tid >> 4, mm = tid & 15;
    double a = -aff_sum[tid] / (double)T_;
    double s = a;
    s += __shfl_xor(s,1); s += __shfl_xor(s,2); s += __shfl_xor(s,4); s += __shfl_xor(s,8);
    double mu = s / 16.0;
    double dd = a - mu;
    double v = dd*dd;
    v += __shfl_xor(v,1); v += __shfl_xor(v,2); v += __shfl_xor(v,4); v += __shfl_xor(v,8);
    double sd = sqrt(v / 15.0);
    double z = dd / (sd + 1e-9);
    double g = (double)bf2f(gates[mm]);
    double pre = z - 1.0/(1.0 + exp(-g));

    int act = (pre > 0.0);
    unsigned long long bal = __ballot(act);
    int nact = __popcll((bal >> (b*16)) & 0xFFFFull);

    double mask;
    if(nact > 0){
      mask = act ? 1.0 : 0.0;
    } else {
      double m1 = z, m2 = -1e300;
      #pragma unroll
      for(int d2=1; d2<16; d2<<=1){
        double o1 = __shfl_xor(m1, d2), o2 = __shfl_xor(m2, d2);
        if(o1 > m1){ m2 = fmax(m1, o2); m1 = o1; }
        else       { m2 = fmax(m2, o1); }
      }
      mask = (z >= m2) ? 1.0 : 0.0;
    }
    int nsel = (nact > 0) ? nact : 2;
    float nmv = (float)(mask / (double)nsel);
    nmL[tid] = nmv;
    if(blockIdx.x == 0){
      store_out(out, flag, OUT_LOG  + tid, (float)pre);
      store_out(out, flag, OUT_MASK + tid, (float)mask);
      nmask_ws[tid] = nmv;
      unsigned long long fb = __ballot((nact==0) && (mm==0));
      if(tid == 0) store_out(out, flag, OUT_FBC, (float)__popcll(fb));
    }
  }
  __syncthreads();

  int idx = blockIdx.x*256 + tid;
  int b = idx >> 16;
  int dh = idx & 65535;
  float acc = 0.f;
  #pragma unroll
  for(int m=0;m<M_;m++) acc += nmL[b*M_+m]*bf2f(ow[m*D_*H_ + dh]);
  dynO[idx] = acc;
}

// ---------------------------------------------------------------------------
// Kernel 5: combined = sum_m nm*sha; final = combined x dynO.
// ---------------------------------------------------------------------------
__global__ __launch_bounds__(256) void final_kernel(
    const unsigned short* __restrict__ shaC, const float* __restrict__ nmask,
    const float* __restrict__ dynO, void* __restrict__ out,
    const int* __restrict__ flagp)
{
  __shared__ float combT[64][36];       // [d][tt], padded
  const int bx = blockIdx.x;            // 128 = b(2) x ttile(64)
  const int b  = bx >> 6;
  const int t0 = (bx & 63) * 32;
  const int h  = blockIdx.y*256 + threadIdx.x;
  const int tid = threadIdx.x;

  float nm[M_];
  #pragma unroll
  for(int m=0;m<M_;m++) nm[m] = nmask[b*M_+m];

  #pragma unroll
  for(int pass=0;pass<8;pass++){
    int idx = pass*256 + tid;
    int d = idx & 63, tt = idx >> 6;
    const unsigned short* sp = shaC + ((long)(b*T_ + t0 + tt)*M_)*D_ + d;
    float a = 0.f;
    #pragma unroll
    for(int m=0;m<M_;m++) a = fmaf(nm[m], bf2f(sp[m*D_]), a);
    combT[d][tt] = a;
  }
  __syncthreads();

  float acc[32];
  #pragma unroll
  for(int tt=0;tt<32;tt++) acc[tt] = 0.f;
  for(int d=0; d<64; d++){
    float g = dynO[((long)b*D_ + d)*H_ + h];
    const floatx4* cp = reinterpret_cast<const floatx4*>(&combT[d][0]);
    #pragma unroll
    for(int c8=0;c8<8;c8++){
      floatx4 cv = cp[c8];
      #pragma unroll
      for(int r=0;r<4;r++) acc[c8*4+r] = fmaf(cv[r], g, acc[c8*4+r]);
    }
  }
  const int flag = *flagp;
  #pragma unroll
  for(int tt=0;tt<32;tt++)
    store_out(out, flag, (long)(b*T_ + t0 + tt)*H_ + h, acc[tt]);
}

// ---------------------------------------------------------------------------
extern "C" void kernel_launch(void* const* d_in, const int* in_sizes, int n_in,
                              void* d_out, int out_size, void* d_ws, size_t ws_size,
                              hipStream_t stream)
{
  (void)in_sizes; (void)n_in; (void)out_size; (void)ws_size;
  char* ws = (char*)d_ws;
  int*    flag  = (int*)(ws);
  double* aff   = (double*)(ws + 64);
  float*  nmask = (float*)(ws + 512);
  float*  dynO  = (float*)(ws + 4096);                        // 512 KB
  unsigned short* canon = (unsigned short*)(ws + (1u<<20));
  unsigned short* c_hid = canon;
  unsigned short* c_ow  = c_hid + N_HID;
  unsigned short* c_gt  = c_ow + N_OW;
  unsigned short* WT    = (unsigned short*)(ws + (size_t)12*1024*1024);
  unsigned short* qb    = (unsigned short*)(ws + (size_t)18*1024*1024);
  unsigned short* kb    = qb + (size_t)B_*M_*T_*D_;
  unsigned short* vT    = kb + (size_t)B_*M_*T_*D_;
  unsigned short* shaC  = vT + (size_t)B_*M_*T_*D_;

  prep_kernel   <<<NB_CONV + 768, 256, 0, stream>>>(
      d_in[0], d_in[1], d_in[2], d_in[3], d_in[4], d_in[5], canon, WT, flag, aff);
  qkv_kernel    <<<dim3(BT_/128, M_),256, 0, stream>>>(c_hid, WT, qb, kb, vT);
  attn_kernel   <<<dim3(T_/128, B_*M_),256,0, stream>>>(qb, kb, vT, shaC, d_out, flag, aff);
  oproj_kernel  <<<512, 256, 0, stream>>>(c_ow, aff, c_gt, d_out, flag, nmask, dynO);
  final_kernel  <<<dim3(128, 4), 256, 0, stream>>>(shaC, nmask, dynO, d_out, flag);
}